// Round 3
// baseline (130.993 us; speedup 1.0000x reference)
//
#include <hip/hip_runtime.h>
#include <math.h>

// LSEP loss: log1p( sum_i sum_{j!=y_i} exp(x[i,j] - x[i,y_i]) )
//   = log1p( sum_i exp(-pos_i) * sum_j exp(x[i,j])  -  B )
// C = 340 -> every float4 lies within one row, row = idx4/85.
//
// n4 = 65536*85 = 5,570,560 = 17 * 256 * 1280:
//   UNROLL=17, 1280 blocks x 256 threads -> exact cover, and 1280 = 5
//   blocks/CU exactly (256 CUs) -> zero tail, zero CU imbalance.
//
// R1 lesson: serialized loop (8 VGPRs) was latency-bound at 64us.
// R2 lesson: ~100us of dur_us is the harness's own reset fills (356MB
// 0xAA poison of d_ws + d_in restore) -- untouchable. Our budget is the
// ~30us of kernel time; drive main to the BW/L3 floor with 17 float4s
// (272B) in flight per thread.

#define NCLS 340
#define NCLS4 85
#define UNROLL 17

__global__ void __launch_bounds__(256) lsep_main(
        const float* __restrict__ in,
        const int* __restrict__ tgt,
        double* __restrict__ partial) {
    const int tid = blockIdx.x * 256 + threadIdx.x;
    const int T = gridDim.x * 256;            // 327,680 threads total
    const float4* __restrict__ in4 = (const float4*)in;

    int   row[UNROLL], t[UNROLL];
    float4 v[UNROLL];
    float pos[UNROLL];

    // epoch 1: all independent loads (17 vector + 17 broadcast tgt)
    #pragma unroll
    for (int u = 0; u < UNROLL; ++u) {
        int idx = tid + u * T;
        row[u] = idx / NCLS4;                 // magic-mul
        v[u]   = in4[idx];
    }
    #pragma unroll
    for (int u = 0; u < UNROLL; ++u)
        t[u] = tgt[row[u]];

    // epoch 2: dependent pos gathers (L1/L2-warm: rows just streamed)
    #pragma unroll
    for (int u = 0; u < UNROLL; ++u)
        pos[u] = in[row[u] * NCLS + t[u]];

    float s = 0.0f;
    #pragma unroll
    for (int u = 0; u < UNROLL; ++u) {
        float e = __expf(v[u].x) + __expf(v[u].y) +
                  __expf(v[u].z) + __expf(v[u].w);
        s += e * __expf(-pos[u]);
    }

    // wave reduce (64 lanes)
    #pragma unroll
    for (int off = 32; off > 0; off >>= 1)
        s += __shfl_down(s, off, 64);

    __shared__ float wsum[4];
    int lane = threadIdx.x & 63;
    int wave = threadIdx.x >> 6;
    if (lane == 0) wsum[wave] = s;
    __syncthreads();
    if (threadIdx.x == 0)
        partial[blockIdx.x] = (double)(wsum[0] + wsum[1] + wsum[2] + wsum[3]);
}

__global__ void __launch_bounds__(256) lsep_reduce(
        const double* __restrict__ partial, int nblocks,
        float* __restrict__ out, int B) {
    double s = 0.0;
    for (int i = threadIdx.x; i < nblocks; i += 256)
        s += partial[i];
    #pragma unroll
    for (int off = 32; off > 0; off >>= 1)
        s += __shfl_down(s, off, 64);
    __shared__ double wsum[4];
    int lane = threadIdx.x & 63;
    int wave = threadIdx.x >> 6;
    if (lane == 0) wsum[wave] = s;
    __syncthreads();
    if (threadIdx.x == 0) {
        double total = wsum[0] + wsum[1] + wsum[2] + wsum[3];
        out[0] = (float)log1p(total - (double)B);   // remove j==y_i terms
    }
}

extern "C" void kernel_launch(void* const* d_in, const int* in_sizes, int n_in,
                              void* d_out, int out_size, void* d_ws, size_t ws_size,
                              hipStream_t stream) {
    const float* in  = (const float*)d_in[0];
    const int*   tgt = (const int*)d_in[1];
    const int B  = in_sizes[1];          // 65536 rows
    const int n4 = in_sizes[0] / 4;      // 5,570,560 float4s

    const int threads = n4 / UNROLL;     // 327,680 (exact)
    const int blocks  = threads / 256;   // 1280 (exact, 5 blocks/CU)

    double* partial = (double*)d_ws;     // 1280 * 8B scratch

    lsep_main<<<blocks, 256, 0, stream>>>(in, tgt, partial);
    lsep_reduce<<<1, 256, 0, stream>>>(partial, blocks, (float*)d_out, B);
}